// Round 1
// 647.792 us; speedup vs baseline: 1.0172x; 1.0172x over previous
//
#include <hip/hip_runtime.h>
#include <hip/hip_bf16.h>
#include <stdint.h>

typedef __bf16 bf16_t;
typedef __bf16 bf16x4 __attribute__((ext_vector_type(4)));
typedef __bf16 bf16x8 __attribute__((ext_vector_type(8)));
typedef float  f32x4  __attribute__((ext_vector_type(4)));

#define SCALE 0.17677669529663687f   // (192/6)^-0.5

__device__ __forceinline__ bf16_t tobf(float f) { return (bf16_t)f; }

__global__ void cvt_weights(const float* __restrict__ qkv_w,
                            const float* __restrict__ proj_w,
                            bf16_t* __restrict__ qkv_wb,
                            bf16_t* __restrict__ proj_wb)
{
  int i = blockIdx.x * 256 + threadIdx.x;
  if (i < 576 * 192) qkv_wb[i] = tobf(qkv_w[i]);
  if (i < 192 * 192) proj_wb[i] = tobf(proj_w[i]);
}

// GEMM1 tile body: xb0/xb1 (x fragments for token-rows half*32+li / half*32+16+li)
// are loaded ONCE per half-pass and reused across all tiles (they don't depend on nt).
#define G1_TILE(NTV, WF)                                                        \
    {                                                                           \
      const int nt_  = (NTV);                                                   \
      const int typ_ = nt_ / 12;            /* 0=q 1=k 2=v */                   \
      if (typ_ < 2) {                                                           \
        float4 qb4 = *(const float4*)(qkv_b + nt_ * 16 + lg * 4);               \
        const int cc_ = (nt_ - typ_ * 12) * 16 + lg * 4;                        \
        const int h_ = cc_ >> 5, dd_ = cc_ & 31;                                \
        bf16_t* dst_ = &shead[h_][typ_ * 2560 + dd_];                           \
        f32x4 a0 = fzero, a1 = fzero;                                           \
        _Pragma("unroll")                                                       \
        for (int kk = 0; kk < 6; ++kk) {                                        \
          a0 = __builtin_amdgcn_mfma_f32_16x16x32_bf16((WF)[kk], xb0[kk], a0, 0, 0, 0); \
          a1 = __builtin_amdgcn_mfma_f32_16x16x32_bf16((WF)[kk], xb1[kk], a1, 0, 0, 0); \
        }                                                                       \
        bf16x4 p0_ = { tobf(a0[0] + qb4.x), tobf(a0[1] + qb4.y),                \
                       tobf(a0[2] + qb4.z), tobf(a0[3] + qb4.w) };              \
        bf16x4 p1_ = { tobf(a1[0] + qb4.x), tobf(a1[1] + qb4.y),                \
                       tobf(a1[2] + qb4.z), tobf(a1[3] + qb4.w) };              \
        *(bf16x4*)&dst_[((half * 2 + 0) * 16 + li) * 40] = p0_;                 \
        *(bf16x4*)&dst_[((half * 2 + 1) * 16 + li) * 40] = p1_;                 \
      } else {                                                                  \
        const float vb_ = qkv_b[nt_ * 16 + li];                                 \
        const int cc_ = (nt_ - 24) * 16 + li;                                   \
        const int h_ = cc_ >> 5, dd_ = cc_ & 31;                                \
        bf16_t* dst_ = &svt[h_][dd_ * 72];                                      \
        f32x4 a0 = fzero, a1 = fzero;                                           \
        _Pragma("unroll")                                                       \
        for (int kk = 0; kk < 6; ++kk) {                                        \
          a0 = __builtin_amdgcn_mfma_f32_16x16x32_bf16(xb0[kk], (WF)[kk], a0, 0, 0, 0); \
          a1 = __builtin_amdgcn_mfma_f32_16x16x32_bf16(xb1[kk], (WF)[kk], a1, 0, 0, 0); \
        }                                                                       \
        bf16x4 p0_ = { tobf(a0[0] + vb_), tobf(a0[1] + vb_),                    \
                       tobf(a0[2] + vb_), tobf(a0[3] + vb_) };                  \
        bf16x4 p1_ = { tobf(a1[0] + vb_), tobf(a1[1] + vb_),                    \
                       tobf(a1[2] + vb_), tobf(a1[3] + vb_) };                  \
        *(bf16x4*)&dst_[(half * 2 + 0) * 16 + lg * 4] = p0_;                    \
        *(bf16x4*)&dst_[(half * 2 + 1) * 16 + lg * 4] = p1_;                    \
      }                                                                         \
    }

// Persistent fused kernel: grid 256 (1/CU), 512 threads (8 waves), 32 windows/block.
// Windows ordered batch-paired: b = bid + 256*(it>>1) + 4096*(it&1), so consecutive
// iterations share one mask window (halves mask HBM fetch; 2nd read is L2/L3 hit).
__global__ __launch_bounds__(512, 2) void winattn_fused(
    const float* __restrict__ x,        // [8192,64,192]
    const float* __restrict__ mask,     // [4096,64,64]
    const float* __restrict__ qkv_b,    // [576]
    const float* __restrict__ proj_b,   // [192]
    const bf16_t* __restrict__ qkv_wb,  // [576,192] bf16
    const bf16_t* __restrict__ proj_wb, // [192,192] bf16
    float* __restrict__ out)            // [8192,64,192]
{
  // LDS: 158720 B (1 block/CU)
  __shared__ __align__(16) bf16_t sbuf[2][64 * 200];     // x staging / attn-out
  __shared__ __align__(16) bf16_t shead[6][2 * 64 * 40]; // per head: q[64][40], k[64][40]
  __shared__ __align__(16) bf16_t svt[6][32 * 72];       // per head vT [32][72]
  __shared__ __align__(16) bf16_t spw[8][16 * 72];       // per wave P/o scratch

  const int tid  = threadIdx.x;
  const int wave = tid >> 6;
  const int lane = tid & 63;
  const int li   = lane & 15;
  const int lg   = lane >> 4;
  const f32x4 fzero = {0.f, 0.f, 0.f, 0.f};

  // ---- hoist weights (constant across windows) ----
  const int jmax = (wave < 4) ? 5 : 4;     // GEMM1 tiles: nt = wave + 8j < 36
  bf16x8 wf_h[2][6];                       // first 2 GEMM1 tiles (48 VGPR)
#pragma unroll
  for (int j = 0; j < 2; ++j) {
    const int nt = wave + 8 * j;
    const bf16_t* wrow = qkv_wb + (size_t)(nt * 16 + li) * 192 + lg * 8;
#pragma unroll
    for (int kk = 0; kk < 6; ++kk) wf_h[j][kk] = *(const bf16x8*)(wrow + kk * 32);
  }
  const int nct = (wave < 4) ? 2 : 1;      // GEMM2 tiles (waves 0-3: 2, waves 4-7: 1)
  bf16x8 wp_h[2][6];                       // proj tiles (48 VGPR)
#pragma unroll
  for (int c = 0; c < 2; ++c) {
    const int ct = (wave < 4) ? (2 * wave + c) : (8 + (wave - 4));
    const bf16_t* wrow = proj_wb + (size_t)(ct * 16 + li) * 192 + lg * 8;
#pragma unroll
    for (int kk = 0; kk < 6; ++kk) wp_h[c][kk] = *(const bf16x8*)(wrow + kk * 32);
  }

  // x-staging address map
  int srow[6], scol[6];
#pragma unroll
  for (int j = 0; j < 6; ++j) {
    int id = tid + 512 * j;
    srow[j] = id / 48;
    scol[j] = (id % 48) * 4;
  }
  float4 pf[6];

  // ---- prologue: stage window blockIdx.x (it=0) into sbuf[0] ----
  {
    const float4* src = (const float4*)(x + (size_t)blockIdx.x * 12288);
#pragma unroll
    for (int j = 0; j < 6; ++j) pf[j] = src[tid + 512 * j];
#pragma unroll
    for (int j = 0; j < 6; ++j) {
      bf16x4 p = { tobf(pf[j].x), tobf(pf[j].y), tobf(pf[j].z), tobf(pf[j].w) };
      *(bf16x4*)&sbuf[0][srow[j] * 200 + scol[j]] = p;
    }
  }
  __syncthreads();

  for (int it = 0; it < 32; ++it) {
    const int b   = blockIdx.x + 256 * (it >> 1) + 4096 * (it & 1);
    const int cur = it & 1;
    bf16_t* sx = sbuf[cur];

    const bool hasNext = (it < 31);
    if (hasNext) {   // prefetch next window's x (regs held through attn phase)
      const int bn = blockIdx.x + 256 * ((it + 1) >> 1) + 4096 * ((it + 1) & 1);
      const float4* src = (const float4*)(x + (size_t)bn * 12288);
#pragma unroll
      for (int j = 0; j < 6; ++j) pf[j] = src[tid + 512 * j];
    }

    // ---- GEMM1: qkv = x @ qkv_w^T + b ----
    // Two half-passes over token rows; x fragments loaded once per pass (12
    // ds_read_b128) and reused across all jmax tiles (was 24 reads PER tile).
#pragma unroll
    for (int half = 0; half < 2; ++half) {
      bf16x8 xb0[6], xb1[6];
#pragma unroll
      for (int kk = 0; kk < 6; ++kk) {
        xb0[kk] = *(const bf16x8*)&sx[((half * 2 + 0) * 16 + li) * 200 + kk * 32 + lg * 8];
        xb1[kk] = *(const bf16x8*)&sx[((half * 2 + 1) * 16 + li) * 200 + kk * 32 + lg * 8];
      }
      // hoisted weight tiles (static index — peeled)
#pragma unroll
      for (int j = 0; j < 2; ++j) {
        G1_TILE(wave + 8 * j, wf_h[j]);
      }
      // remaining tiles: weights streamed from global (L2-resident)
      for (int j = 2; j < jmax; ++j) {
        const int nt = wave + 8 * j;
        bf16x8 wf[6];
        const bf16_t* wrow = qkv_wb + (size_t)(nt * 16 + li) * 192 + lg * 8;
#pragma unroll
        for (int kk = 0; kk < 6; ++kk) wf[kk] = *(const bf16x8*)(wrow + kk * 32);
        G1_TILE(nt, wf);
      }
    }
    __syncthreads();   // barrier A: qkv ready

    // ---- mask burst: all 3 units' rows, one latency ----
    float4 mreg[3][4];
    {
      const float* maskw = mask + (size_t)(b & 4095) * 4096;
#pragma unroll
      for (int uu = 0; uu < 3; ++uu) {
        const int ntu = (wave * 3 + uu) & 3;
        const float* mrow = maskw + (ntu * 16 + li) * 64 + lg * 4;
#pragma unroll
        for (int mt = 0; mt < 4; ++mt) mreg[uu][mt] = *(const float4*)(mrow + mt * 16);
      }
    }

    // ---- attention: 24 units, 3 per wave ----
#pragma unroll
    for (int uu = 0; uu < 3; ++uu) {
      const int unit = wave * 3 + uu;
      const int h  = unit >> 2;
      const int nt = unit & 3;
      const bf16_t* sq = &shead[h][0];
      const bf16_t* sk = &shead[h][2560];
      bf16x8 qf = *(const bf16x8*)&sq[(nt * 16 + li) * 40 + lg * 8];
      f32x4 sacc[4];
#pragma unroll
      for (int mt = 0; mt < 4; ++mt) {
        bf16x8 kf = *(const bf16x8*)&sk[(mt * 16 + li) * 40 + lg * 8];
        sacc[mt] = __builtin_amdgcn_mfma_f32_16x16x32_bf16(kf, qf, fzero, 0, 0, 0);
      }
      float vals[16];
      float rmax = -3.0e38f;
#pragma unroll
      for (int mt = 0; mt < 4; ++mt)
#pragma unroll
        for (int r = 0; r < 4; ++r) {
          float v = sacc[mt][r] * SCALE + ((const float*)&mreg[uu][mt])[r];
          vals[mt * 4 + r] = v;
          rmax = fmaxf(rmax, v);
        }
      rmax = fmaxf(rmax, __shfl_xor(rmax, 16));
      rmax = fmaxf(rmax, __shfl_xor(rmax, 32));
      float rsum = 0.f;
#pragma unroll
      for (int e = 0; e < 16; ++e) {
        float t = __expf(vals[e] - rmax);
        vals[e] = t;
        rsum += t;
      }
      rsum += __shfl_xor(rsum, 16);
      rsum += __shfl_xor(rsum, 32);
      const float inv = __builtin_amdgcn_rcpf(rsum);
      bf16_t* P = spw[wave];
#pragma unroll
      for (int mt = 0; mt < 4; ++mt) {
        bf16x4 p = { tobf(vals[mt * 4 + 0] * inv), tobf(vals[mt * 4 + 1] * inv),
                     tobf(vals[mt * 4 + 2] * inv), tobf(vals[mt * 4 + 3] * inv) };
        *(bf16x4*)&P[li * 72 + mt * 16 + lg * 4] = p;
      }
      __asm__ volatile("s_waitcnt lgkmcnt(0)" ::: "memory");
      f32x4 o0 = fzero, o1 = fzero;
#pragma unroll
      for (int ks = 0; ks < 2; ++ks) {
        bf16x8 pfr = *(const bf16x8*)&P[li * 72 + ks * 32 + lg * 8];
        bf16x8 v0  = *(const bf16x8*)&svt[h][li * 72 + ks * 32 + lg * 8];
        bf16x8 v1  = *(const bf16x8*)&svt[h][(16 + li) * 72 + ks * 32 + lg * 8];
        o0 = __builtin_amdgcn_mfma_f32_16x16x32_bf16(v0, pfr, o0, 0, 0, 0);
        o1 = __builtin_amdgcn_mfma_f32_16x16x32_bf16(v1, pfr, o1, 0, 0, 0);
      }
      bf16x4 p0 = { tobf(o0[0]), tobf(o0[1]), tobf(o0[2]), tobf(o0[3]) };
      bf16x4 p1 = { tobf(o1[0]), tobf(o1[1]), tobf(o1[2]), tobf(o1[3]) };
      bf16_t* so = &sx[(nt * 16 + li) * 200 + h * 32 + lg * 4];
      *(bf16x4*)&so[0]  = p0;
      *(bf16x4*)&so[16] = p1;
    }

    // write prefetched next-window x into the other buffer
    if (hasNext) {
      bf16_t* nx = sbuf[cur ^ 1];
#pragma unroll
      for (int j = 0; j < 6; ++j) {
        bf16x4 p = { tobf(pf[j].x), tobf(pf[j].y), tobf(pf[j].z), tobf(pf[j].w) };
        *(bf16x4*)&nx[srow[j] * 200 + scol[j]] = p;
      }
    }
    __syncthreads();   // barrier B: attn-out + next-x staged

    // ---- GEMM2: out = so @ proj_w^T + proj_b ----
    // Half-pass structure: attn-out fragments loaded once (12 ds_read_b128)
    // and reused across both ct tiles.
    {
      float* ob = out + (size_t)b * 12288;
#pragma unroll
      for (int half = 0; half < 2; ++half) {
        bf16x8 sb0[6], sb1[6];
#pragma unroll
        for (int kk = 0; kk < 6; ++kk) {
          sb0[kk] = *(const bf16x8*)&sx[((half * 2 + 0) * 16 + li) * 200 + kk * 32 + lg * 8];
          sb1[kk] = *(const bf16x8*)&sx[((half * 2 + 1) * 16 + li) * 200 + kk * 32 + lg * 8];
        }
#pragma unroll
        for (int c = 0; c < 2; ++c) {
          if (c < nct) {
            const int ct = (wave < 4) ? (2 * wave + c) : (8 + (wave - 4));
            float4 pb = *(const float4*)(proj_b + ct * 16 + lg * 4);
            f32x4 a0 = fzero, a1 = fzero;
#pragma unroll
            for (int kk = 0; kk < 6; ++kk) {
              a0 = __builtin_amdgcn_mfma_f32_16x16x32_bf16(wp_h[c][kk], sb0[kk], a0, 0, 0, 0);
              a1 = __builtin_amdgcn_mfma_f32_16x16x32_bf16(wp_h[c][kk], sb1[kk], a1, 0, 0, 0);
            }
            float4 o0 = { a0[0] + pb.x, a0[1] + pb.y, a0[2] + pb.z, a0[3] + pb.w };
            float4 o1 = { a1[0] + pb.x, a1[1] + pb.y, a1[2] + pb.z, a1[3] + pb.w };
            *(float4*)(ob + (size_t)((half * 2 + 0) * 16 + li) * 192 + ct * 16 + lg * 4) = o0;
            *(float4*)(ob + (size_t)((half * 2 + 1) * 16 + li) * 192 + ct * 16 + lg * 4) = o1;
          }
        }
      }
    }
    // no barrier: next window's GEMM1 touches shead/svt only and reads
    // sbuf[cur^1]; the next prefetch-write to sbuf[cur] is ordered by barrier A.
  }
}

extern "C" void kernel_launch(void* const* d_in, const int* in_sizes, int n_in,
                              void* d_out, int out_size, void* d_ws, size_t ws_size,
                              hipStream_t stream) {
  const float* x      = (const float*)d_in[0];
  const float* mask   = (const float*)d_in[1];
  const float* qkv_w  = (const float*)d_in[2];
  const float* qkv_b  = (const float*)d_in[3];
  const float* proj_w = (const float*)d_in[4];
  const float* proj_b = (const float*)d_in[5];
  float* out = (float*)d_out;

  bf16_t* qkv_wb  = (bf16_t*)d_ws;
  bf16_t* proj_wb = qkv_wb + 576 * 192;

  cvt_weights<<<432, 256, 0, stream>>>(qkv_w, proj_w, qkv_wb, proj_wb);
  winattn_fused<<<256, 512, 0, stream>>>(x, mask, qkv_b, proj_b, qkv_wb, proj_wb, out);
}